// Round 5
// baseline (448.236 us; speedup 1.0000x reference)
//
#include <hip/hip_runtime.h>

// ---------------------------------------------------------------------------
// entropy_57346403336670:
//   C = normalize_rows(ex) @ normalize_rows(ey)^T   (16384 x 16384, K=256)
//   e1 = -sum(exp(lp(rowmax))*lp(rowmax)), e2 = same over colmax
// R5 (= R4 + sched_barrier hardening): persistent 256-block supertile GEMM
//     with T3+T4 counted-vmcnt pipeline. 256 phases/block; each phase: stage
//     one 16KB k-slice 4 phases ahead, s_waitcnt vmcnt(8) (NEVER 0), raw
//     s_barrier, sched_barrier(0) fences (rule #18), 6 ds_read_b128, 8 MFMA
//     (setprio-wrapped). Slices are disjoint LDS regions -> 1 barrier/phase
//     is race-free. Per-slice 8-group XOR bank swizzle (gray-code inverse on
//     the staging source). Fused row/col max epilogue via LDS atomics.
// ---------------------------------------------------------------------------

typedef _Float16 f16x8 __attribute__((ext_vector_type(8)));
typedef _Float16 f16x4 __attribute__((ext_vector_type(4)));
typedef float f32x16 __attribute__((ext_vector_type(16)));

#define NROWS 16384
#define KDIM 256

__device__ inline void gl_lds16(const void* g, void* l) {
  __builtin_amdgcn_global_load_lds(
      (const __attribute__((address_space(1))) void*)g,
      (__attribute__((address_space(3))) void*)l, 16, 0, 0);
}

// monotone float->uint transform (order-preserving)
__device__ inline unsigned f2mono(float f) {
  unsigned b = __float_as_uint(f);
  return (b & 0x80000000u) ? ~b : (b | 0x80000000u);
}
__device__ inline float mono2f(unsigned u) {
  return __uint_as_float((u & 0x80000000u) ? (u ^ 0x80000000u) : ~u);
}

// invert y = x ^ (x>>1) on 4 bits (decode the staging granule -> source slot)
__device__ inline int graydec4(int y) {
  int x3 = (y >> 3) & 1;
  int x2 = ((y >> 2) & 1) ^ x3;
  int x1 = ((y >> 1) & 1) ^ x2;
  int x0 = (y & 1) ^ x1;
  return (x3 << 3) | (x2 << 2) | (x1 << 1) | x0;
}

// --------------------------- normalize + cast ------------------------------
__global__ __launch_bounds__(256) void normalize_k(
    const float* __restrict__ ex, const float* __restrict__ ey,
    _Float16* __restrict__ xn, _Float16* __restrict__ yn) {
  const int lane = threadIdx.x & 63;
  const int row = blockIdx.x * 4 + (threadIdx.x >> 6);
  const float* src;
  _Float16* dst;
  if (row < NROWS) {
    src = ex + (size_t)row * KDIM;
    dst = xn + (size_t)row * KDIM;
  } else {
    src = ey + (size_t)(row - NROWS) * KDIM;
    dst = yn + (size_t)(row - NROWS) * KDIM;
  }
  float4 v = *reinterpret_cast<const float4*>(src + lane * 4);
  float ss = v.x * v.x + v.y * v.y + v.z * v.z + v.w * v.w;
#pragma unroll
  for (int m = 1; m <= 32; m <<= 1) ss += __shfl_xor(ss, m, 64);
  float inv = 1.0f / fmaxf(sqrtf(ss), 1e-8f);
  f16x4 o;
  o[0] = (_Float16)(v.x * inv);
  o[1] = (_Float16)(v.y * inv);
  o[2] = (_Float16)(v.z * inv);
  o[3] = (_Float16)(v.w * inv);
  *reinterpret_cast<f16x4*>(dst + lane * 4) = o;
}

// ------------------------------ GEMM + max ---------------------------------
// LDS: 2 buffers x 64KB. Buffer = [A: 4 slices x 8KB][B: 4 slices x 8KB].
// Slice = 256 rows x 16 k-halves. Granule (16B) for (row R, half h) sits at
// index (2R+h) ^ (R&7): a wave b128 fragment read (rows base+lane&31,
// h=lane>>5) covers all 8 bank groups per 8 lanes = conflict-free.
// gl_lds writes LDS linearly (granule = tid), so the staging SOURCE (row,h)
// for granule g is the XOR-decode inverse (rule #21).
__global__ __launch_bounds__(512, 2) void gemm_max_k(
    const _Float16* __restrict__ X, const _Float16* __restrict__ Y,
    unsigned* __restrict__ rmax, unsigned* __restrict__ cmax) {
  __shared__ __align__(16) char smem[133120];  // 128KB buffers + 2KB reduce

  const int tid = threadIdx.x;
  const int lane = tid & 63;
  const int wid = tid >> 6;  // 0..7
  const int wr = wid >> 2;   // 0..1 : rows wr*128..+127
  const int wc = wid & 3;    // 0..3 : cols wc*64..+63
  const int h = lane >> 5;   // half-wave (k-half selector in frags)

  // block -> 4x4 supertile; XCD x owns a compact 2-super-row band
  const int bid = blockIdx.x;
  const int lid = bid >> 3;
  const int sm4 = ((bid & 7) * 2 + (lid >> 4)) * 4;  // tile-row base
  const int sn4 = (lid & 15) * 4;                    // tile-col base

  // ---- staging source decode: thread t owns granule g = t of each slice ----
  const int x4 = graydec4(tid & 15);
  const int srow = ((tid >> 4) << 3) | (x4 >> 1);  // 0..255
  const int sh8 = (x4 & 1) * 8;                    // k-half offset (halves)
  const _Float16* xsrc0 = X + (size_t)srow * KDIM + sh8;
  const _Float16* ysrc0 = Y + (size_t)srow * KDIM + sh8;

  // ---- fragment read offsets ----
  const int al16 = ((2 * (lane & 31) + h) ^ (lane & 7)) << 4;  // byte in slice
  int arow[4], brow[2];
#pragma unroll
  for (int m = 0; m < 4; ++m) arow[m] = (wr * 128 + m * 32) * 32;  // bytes
#pragma unroll
  for (int n = 0; n < 2; ++n) brow[n] = (wc * 64 + n * 32) * 32;

  unsigned* rs = (unsigned*)(smem + 131072);  // [256] row maxes
  unsigned* cs = rs + 256;                    // [256] col maxes
  rs[tid] = 0;                                // covers rs+cs (512 slots)
  __syncthreads();                            // no loads in flight yet

  const f32x16 vzero = {};
  f32x16 acc[4][2] = {};

  // ---- stage helper (unit u = global phase; 4 units = one K-step) ----
  auto stage = [&](int u) {
    const int uu = u & 255;
    const int su = uu >> 2;  // step 0..63
    const int pu = uu & 3;   // slice
    const int tu = su >> 2;  // tile 0..15
    const int tmu = sm4 + (tu & 3);
    const int tnu = sn4 + (tu >> 2);
    const int kofs = (su & 3) * 64 + pu * 16;
    const int lb = ((su & 1) << 16) + (pu << 13);
    gl_lds16(xsrc0 + (((size_t)tmu << 16) + kofs), smem + lb + tid * 16);
    gl_lds16(ysrc0 + (((size_t)tnu << 16) + kofs), smem + lb + 32768 + tid * 16);
  };

  // prologue: units 0..3 (step 0, buffer 0)
#pragma unroll
  for (int p = 0; p < 4; ++p) stage(p);

  for (int s = 0; s < 64; ++s) {
    const int bo = (s & 1) << 16;  // read buffer
#pragma unroll
    for (int p = 0; p < 4; ++p) {
      stage(s * 4 + p + 4);
      // slice p of step s was issued 4 phases ago; 4 newer units (8 loads)
      // may remain in flight. NEVER drain to 0.
      asm volatile("s_waitcnt vmcnt(8)" ::: "memory");
      __builtin_amdgcn_sched_barrier(0);  // rule #18: pin nothing above this
      __builtin_amdgcn_s_barrier();       // all waves' slice-p chunks landed
      __builtin_amdgcn_sched_barrier(0);
      const int sb = bo + (p << 13);
      f16x8 a0 = *(const f16x8*)(smem + sb + arow[0] + al16);
      f16x8 a1 = *(const f16x8*)(smem + sb + arow[1] + al16);
      f16x8 a2 = *(const f16x8*)(smem + sb + arow[2] + al16);
      f16x8 a3 = *(const f16x8*)(smem + sb + arow[3] + al16);
      f16x8 b0 = *(const f16x8*)(smem + sb + 32768 + brow[0] + al16);
      f16x8 b1 = *(const f16x8*)(smem + sb + 32768 + brow[1] + al16);
      __builtin_amdgcn_s_setprio(1);
      acc[0][0] = __builtin_amdgcn_mfma_f32_32x32x16_f16(a0, b0, acc[0][0], 0, 0, 0);
      acc[0][1] = __builtin_amdgcn_mfma_f32_32x32x16_f16(a0, b1, acc[0][1], 0, 0, 0);
      acc[1][0] = __builtin_amdgcn_mfma_f32_32x32x16_f16(a1, b0, acc[1][0], 0, 0, 0);
      acc[1][1] = __builtin_amdgcn_mfma_f32_32x32x16_f16(a1, b1, acc[1][1], 0, 0, 0);
      acc[2][0] = __builtin_amdgcn_mfma_f32_32x32x16_f16(a2, b0, acc[2][0], 0, 0, 0);
      acc[2][1] = __builtin_amdgcn_mfma_f32_32x32x16_f16(a2, b1, acc[2][1], 0, 0, 0);
      acc[3][0] = __builtin_amdgcn_mfma_f32_32x32x16_f16(a3, b0, acc[3][0], 0, 0, 0);
      acc[3][1] = __builtin_amdgcn_mfma_f32_32x32x16_f16(a3, b1, acc[3][1], 0, 0, 0);
      __builtin_amdgcn_s_setprio(0);
    }

    if ((s & 3) == 3) {
      // ---- per-tile fused max epilogue (no vmcnt drain!) ----
      const int tm = sm4 + ((s >> 2) & 3);
      const int tn = sn4 + (s >> 4);
      // C/D 32x32 layout: col = lane&31, row = (r&3) + 8*(r>>2) + 4*h
#pragma unroll
      for (int m = 0; m < 4; ++m) {
#pragma unroll
        for (int r = 0; r < 16; ++r) {
          float v = fmaxf(acc[m][0][r], acc[m][1][r]);
#pragma unroll
          for (int msk = 1; msk <= 16; msk <<= 1)
            v = fmaxf(v, __shfl_xor(v, msk, 64));
          if ((lane & 31) == 0)
            atomicMax(&rs[wr * 128 + m * 32 + (r & 3) + 8 * (r >> 2) + 4 * h],
                      f2mono(v));
        }
      }
#pragma unroll
      for (int n = 0; n < 2; ++n) {
        float v = -1e30f;
#pragma unroll
        for (int m = 0; m < 4; ++m)
#pragma unroll
          for (int r = 0; r < 16; ++r) v = fmaxf(v, acc[m][n][r]);
        v = fmaxf(v, __shfl_xor(v, 32, 64));
        if (lane < 32) atomicMax(&cs[wc * 64 + n * 32 + lane], f2mono(v));
      }
      asm volatile("s_waitcnt lgkmcnt(0)" ::: "memory");
      __builtin_amdgcn_sched_barrier(0);
      __builtin_amdgcn_s_barrier();  // rs/cs complete; vmcnt stays in flight
      __builtin_amdgcn_sched_barrier(0);
      if (tid < 256) {
        atomicMax(&rmax[tm * 256 + tid], rs[tid]);
        rs[tid] = 0;
      } else {
        atomicMax(&cmax[tn * 256 + (tid - 256)], cs[tid - 256]);
        cs[tid - 256] = 0;
      }
#pragma unroll
      for (int m = 0; m < 4; ++m)
#pragma unroll
        for (int n = 0; n < 2; ++n) acc[m][n] = vzero;
    }
  }
}

// ------------------------------ finalize -----------------------------------
__global__ __launch_bounds__(256) void finalize_k(
    const unsigned* __restrict__ rmax, const unsigned* __restrict__ cmax,
    float* __restrict__ out) {
  const unsigned* src = (blockIdx.x == 0) ? rmax : cmax;
  float sum = 0.0f;
  for (int i = threadIdx.x; i < NROWS; i += 256) {
    float v = mono2f(src[i]);
    float d = v - 1.0f;
    // lp = -d^2/(2*0.3^2) - (log(0.3)+0.5*log(2pi))
    float lp = fmaf(-d * d, 5.5555555556f, 0.2850342717f);
    sum += expf(lp) * lp;
  }
#pragma unroll
  for (int m = 1; m <= 32; m <<= 1) sum += __shfl_xor(sum, m, 64);
  __shared__ float partial[4];
  if ((threadIdx.x & 63) == 0) partial[threadIdx.x >> 6] = sum;
  __syncthreads();
  if (threadIdx.x == 0)
    out[blockIdx.x] = -(partial[0] + partial[1] + partial[2] + partial[3]);
}

// ---------------------------------------------------------------------------
extern "C" void kernel_launch(void* const* d_in, const int* in_sizes, int n_in,
                              void* d_out, int out_size, void* d_ws, size_t ws_size,
                              hipStream_t stream) {
  const float* ex = (const float*)d_in[0];
  const float* ey = (const float*)d_in[1];
  char* wsb = (char*)d_ws;
  // ws layout: xn f16 8MB | yn f16 8MB | rmax 64KB | cmax 64KB
  _Float16* xn = (_Float16*)wsb;
  _Float16* yn = (_Float16*)(wsb + 8388608);
  unsigned* rmax = (unsigned*)(wsb + 16777216);
  unsigned* cmax = (unsigned*)(wsb + 16777216 + 65536);

  hipMemsetAsync(wsb + 16777216, 0, 131072, stream);  // mono-floor = 0
  normalize_k<<<8192, 256, 0, stream>>>(ex, ey, xn, yn);
  gemm_max_k<<<256, 512, 0, stream>>>(xn, yn, rmax, cmax);
  finalize_k<<<2, 256, 0, stream>>>(rmax, cmax, (float*)d_out);
}

// Round 9
// 396.467 us; speedup vs baseline: 1.1306x; 1.1306x over previous
//
#include <hip/hip_runtime.h>

// ---------------------------------------------------------------------------
// entropy_57346403336670:
//   C = normalize_rows(ex) @ normalize_rows(ey)^T   (16384 x 16384, K=256)
//   e1 = -sum(exp(lp(rowmax))*lp(rowmax)), e2 = same over colmax
// R9 (= R7/R8 resubmit; both hit GPU-acquisition timeouts): LDS-free GEMM.
//     normalize_k writes panels in MFMA fragment-chunk layout (chunk =
//     rowblk*16 + kblk; 1024 B = lane*16B fragment), so the GEMM loads every
//     A/B fragment as ONE coalesced global_load_dwordx4 straight to
//     registers (L1/L2-resident) — no LDS staging, no barriers, no swizzle,
//     nothing to drain. Epilogue row-max uses DPP row_ror reductions (VALU)
//     instead of ds_swizzle chains; per-block LDS max combine, then one
//     global atomicMax pass. No C materialized.
// ---------------------------------------------------------------------------

typedef _Float16 f16x8 __attribute__((ext_vector_type(8)));
typedef _Float16 f16x4 __attribute__((ext_vector_type(4)));
typedef float f32x16 __attribute__((ext_vector_type(16)));

#define NROWS 16384
#define KDIM 256

// monotone float->uint transform (order-preserving)
__device__ inline unsigned f2mono(float f) {
  unsigned b = __float_as_uint(f);
  return (b & 0x80000000u) ? ~b : (b | 0x80000000u);
}
__device__ inline float mono2f(unsigned u) {
  return __uint_as_float((u & 0x80000000u) ? (u ^ 0x80000000u) : ~u);
}

// max with a DPP-rotated copy (row_ror:N within 16-lane rows; pure VALU).
// CTRL must be a compile-time constant -> template parameter.
template <int CTRL>
__device__ inline float dppmax(float v) {
  int r = __builtin_amdgcn_update_dpp(0, __float_as_int(v), CTRL, 0xf, 0xf, true);
  return fmaxf(v, __int_as_float(r));
}

// --------------------------- normalize + cast + tile -----------------------
// One wave per row. Output layout: panel = [rb:512][kb:16][lane:64][16B],
// where fragment lane l = (k-half h)*32 + (row&31), holding k = kb*16+h*8..+8.
// Writer lane l covers k0 = l*4: kb = l>>2, h = (l>>1)&1, sub = l&1 (8B).
__global__ __launch_bounds__(256) void normalize_k(
    const float* __restrict__ ex, const float* __restrict__ ey,
    _Float16* __restrict__ xn, _Float16* __restrict__ yn) {
  const int lane = threadIdx.x & 63;
  const int row = blockIdx.x * 4 + (threadIdx.x >> 6);
  const float* src;
  _Float16* dst;
  int r;
  if (row < NROWS) {
    src = ex + (size_t)row * KDIM;
    dst = xn;
    r = row;
  } else {
    src = ey + (size_t)(row - NROWS) * KDIM;
    dst = yn;
    r = row - NROWS;
  }
  float4 v = *reinterpret_cast<const float4*>(src + lane * 4);
  float ss = v.x * v.x + v.y * v.y + v.z * v.z + v.w * v.w;
#pragma unroll
  for (int m = 1; m <= 32; m <<= 1) ss += __shfl_xor(ss, m, 64);
  float inv = 1.0f / fmaxf(sqrtf(ss), 1e-8f);
  f16x4 o;
  o[0] = (_Float16)(v.x * inv);
  o[1] = (_Float16)(v.y * inv);
  o[2] = (_Float16)(v.z * inv);
  o[3] = (_Float16)(v.w * inv);
  // scatter to fragment-chunk layout (8 B per lane)
  const int kb = lane >> 2, h = (lane >> 1) & 1, sub = lane & 1;
  const size_t chunk = (size_t)(r >> 5) * 16 + kb;   // *1024 B = *512 halves
  const size_t off = chunk * 512 + (h * 32 + (r & 31)) * 8 + sub * 4;
  *reinterpret_cast<f16x4*>(dst + off) = o;
}

// ------------------------------ GEMM + max ---------------------------------
// 256x256 tile, 8 waves (2x4), wave-tile 128x64, mfma_f32_32x32x16_f16,
// BK=16 per step, 16 steps. All operands loaded fragment-at-a-time by
// coalesced dwordx4 from the pre-tiled panels. No LDS in the loop.
__global__ __launch_bounds__(512, 2) void gemm_max_k(
    const _Float16* __restrict__ Xf, const _Float16* __restrict__ Yf,
    unsigned* __restrict__ rmax, unsigned* __restrict__ cmax) {
  __shared__ unsigned red[512];  // [0..255] row maxes, [256..511] col maxes

  const int tid = threadIdx.x;
  const int lane = tid & 63;
  const int wid = tid >> 6;  // 0..7
  const int wr = wid >> 2;   // 0..1 : rows wr*128..+127
  const int wc = wid & 3;    // 0..3 : cols wc*64..+63

  // XCD swizzle: 4096 blocks, bijective (4096 % 8 == 0)
  const int bid = blockIdx.x;
  const int wg = (bid & 7) * 512 + (bid >> 3);
  const int tm = wg >> 6;  // 0..63
  const int tn = wg & 63;  // 0..63

  red[tid] = 0;
  __syncthreads();

  // fragment base pointers (halves): chunk(rb,kb) at rb*8192 + kb*512
  const _Float16* abase =
      Xf + (size_t)(tm * 8 + wr * 4) * 8192 + lane * 8;
  const _Float16* bbase =
      Yf + (size_t)(tn * 8 + wc * 2) * 8192 + lane * 8;

  f32x16 acc[4][2] = {};

#pragma unroll
  for (int kt = 0; kt < 16; ++kt) {
    f16x8 a0 = *(const f16x8*)(abase + 0 * 8192 + kt * 512);
    f16x8 a1 = *(const f16x8*)(abase + 1 * 8192 + kt * 512);
    f16x8 a2 = *(const f16x8*)(abase + 2 * 8192 + kt * 512);
    f16x8 a3 = *(const f16x8*)(abase + 3 * 8192 + kt * 512);
    f16x8 b0 = *(const f16x8*)(bbase + 0 * 8192 + kt * 512);
    f16x8 b1 = *(const f16x8*)(bbase + 1 * 8192 + kt * 512);
    acc[0][0] = __builtin_amdgcn_mfma_f32_32x32x16_f16(a0, b0, acc[0][0], 0, 0, 0);
    acc[0][1] = __builtin_amdgcn_mfma_f32_32x32x16_f16(a0, b1, acc[0][1], 0, 0, 0);
    acc[1][0] = __builtin_amdgcn_mfma_f32_32x32x16_f16(a1, b0, acc[1][0], 0, 0, 0);
    acc[1][1] = __builtin_amdgcn_mfma_f32_32x32x16_f16(a1, b1, acc[1][1], 0, 0, 0);
    acc[2][0] = __builtin_amdgcn_mfma_f32_32x32x16_f16(a2, b0, acc[2][0], 0, 0, 0);
    acc[2][1] = __builtin_amdgcn_mfma_f32_32x32x16_f16(a2, b1, acc[2][1], 0, 0, 0);
    acc[3][0] = __builtin_amdgcn_mfma_f32_32x32x16_f16(a3, b0, acc[3][0], 0, 0, 0);
    acc[3][1] = __builtin_amdgcn_mfma_f32_32x32x16_f16(a3, b1, acc[3][1], 0, 0, 0);
  }

  // ---- epilogue ----
  // C/D 32x32 layout: col = lane&31, row = (r&3) + 8*(r>>2) + 4*(lane>>5)
  // Row max: DPP ror 8/4/2/1 reduces each 16-lane group (VALU), one
  // shfl_xor(16) merges the two groups of a 32-lane half -> full row max.
#pragma unroll
  for (int m = 0; m < 4; ++m) {
#pragma unroll
    for (int r = 0; r < 16; ++r) {
      float v = fmaxf(acc[m][0][r], acc[m][1][r]);
      v = dppmax<0x128>(v);  // row_ror:8
      v = dppmax<0x124>(v);  // row_ror:4
      v = dppmax<0x122>(v);  // row_ror:2
      v = dppmax<0x121>(v);  // row_ror:1
      v = fmaxf(v, __shfl_xor(v, 16, 64));
      if ((lane & 31) == 0)
        atomicMax(&red[wr * 128 + m * 32 + (r & 3) + 8 * (r >> 2) +
                       4 * (lane >> 5)],
                  f2mono(v));
    }
  }
  // Col max: per-lane reduce over m,r (VALU), merge halves via shfl_xor(32).
#pragma unroll
  for (int n = 0; n < 2; ++n) {
    float v = acc[0][n][0];
#pragma unroll
    for (int m = 0; m < 4; ++m)
#pragma unroll
      for (int r = 0; r < 16; ++r) v = fmaxf(v, acc[m][n][r]);
    v = fmaxf(v, __shfl_xor(v, 32, 64));
    if (lane < 32) atomicMax(&red[256 + wc * 64 + n * 32 + lane], f2mono(v));
  }
  __syncthreads();

  // one dense global-atomic pass per block
  if (tid < 256)
    atomicMax(&rmax[tm * 256 + tid], red[tid]);
  else
    atomicMax(&cmax[tn * 256 + (tid - 256)], red[tid]);
}

// ------------------------------ finalize -----------------------------------
__global__ __launch_bounds__(256) void finalize_k(
    const unsigned* __restrict__ rmax, const unsigned* __restrict__ cmax,
    float* __restrict__ out) {
  const unsigned* src = (blockIdx.x == 0) ? rmax : cmax;
  float sum = 0.0f;
  for (int i = threadIdx.x; i < NROWS; i += 256) {
    float v = mono2f(src[i]);
    float d = v - 1.0f;
    // lp = -d^2/(2*0.3^2) - (log(0.3)+0.5*log(2pi))
    float lp = fmaf(-d * d, 5.5555555556f, 0.2850342717f);
    sum += expf(lp) * lp;
  }
#pragma unroll
  for (int m = 1; m <= 32; m <<= 1) sum += __shfl_xor(sum, m, 64);
  __shared__ float partial[4];
  if ((threadIdx.x & 63) == 0) partial[threadIdx.x >> 6] = sum;
  __syncthreads();
  if (threadIdx.x == 0)
    out[blockIdx.x] = -(partial[0] + partial[1] + partial[2] + partial[3]);
}

// ---------------------------------------------------------------------------
extern "C" void kernel_launch(void* const* d_in, const int* in_sizes, int n_in,
                              void* d_out, int out_size, void* d_ws, size_t ws_size,
                              hipStream_t stream) {
  const float* ex = (const float*)d_in[0];
  const float* ey = (const float*)d_in[1];
  char* wsb = (char*)d_ws;
  // ws layout: xn f16 8MB (tiled) | yn f16 8MB (tiled) | rmax 64KB | cmax 64KB
  _Float16* xn = (_Float16*)wsb;
  _Float16* yn = (_Float16*)(wsb + 8388608);
  unsigned* rmax = (unsigned*)(wsb + 16777216);
  unsigned* cmax = (unsigned*)(wsb + 16777216 + 65536);

  (void)hipMemsetAsync(wsb + 16777216, 0, 131072, stream);  // mono-floor = 0
  normalize_k<<<8192, 256, 0, stream>>>(ex, ey, xn, yn);
  gemm_max_k<<<4096, 512, 0, stream>>>(xn, yn, rmax, cmax);
  finalize_k<<<2, 256, 0, stream>>>(rmax, cmax, (float*)d_out);
}

// Round 12
// 342.559 us; speedup vs baseline: 1.3085x; 1.1574x over previous
//
#include <hip/hip_runtime.h>

// ---------------------------------------------------------------------------
// entropy_57346403336670:
//   C = normalize_rows(ex) @ normalize_rows(ey)^T   (16384 x 16384, K=256)
//   e1 = -sum(exp(lp(rowmax))*lp(rowmax)), e2 = same over colmax
// R12 (= R10/R11 resubmit; both hit GPU-acquisition timeouts):
//      fragment-layout panels (R9) + LDS pipeline (T3/T4). Per K-step the
//      block stages A+B k-slices (16 KB) via LINEAR global_load_lds (panels
//      are pre-tiled -> contiguous source, linear LDS, no swizzle), 3-buffer
//      ring, depth-2 prefetch, s_waitcnt vmcnt(2) (never 0 mid-loop), one raw
//      s_barrier per step. Fragment ds_reads are contiguous 1024 B/wave ->
//      conflict-free. XCD-square tile traversal keeps each square's 2 MB
//      working set L2-resident. DPP epilogue (R9). No C materialized.
// ---------------------------------------------------------------------------

typedef _Float16 f16x8 __attribute__((ext_vector_type(8)));
typedef _Float16 f16x4 __attribute__((ext_vector_type(4)));
typedef float f32x16 __attribute__((ext_vector_type(16)));

#define NROWS 16384
#define KDIM 256

__device__ inline void gl_lds16(const void* g, void* l) {
  __builtin_amdgcn_global_load_lds(
      (const __attribute__((address_space(1))) void*)g,
      (__attribute__((address_space(3))) void*)l, 16, 0, 0);
}

// monotone float->uint transform (order-preserving)
__device__ inline unsigned f2mono(float f) {
  unsigned b = __float_as_uint(f);
  return (b & 0x80000000u) ? ~b : (b | 0x80000000u);
}
__device__ inline float mono2f(unsigned u) {
  return __uint_as_float((u & 0x80000000u) ? (u ^ 0x80000000u) : ~u);
}

// max with a DPP-rotated copy (row_ror:N within 16-lane rows; pure VALU)
template <int CTRL>
__device__ inline float dppmax(float v) {
  int r = __builtin_amdgcn_update_dpp(0, __float_as_int(v), CTRL, 0xf, 0xf, true);
  return fmaxf(v, __int_as_float(r));
}

// --------------------------- normalize + cast + tile -----------------------
// One wave per row. Output: panel chunks of 1024 B: chunk(rb, kb) at byte
// rb*16384 + kb*1024; within chunk lane l = h*32 + (row&31) holds k =
// kb*16 + h*8 .. +8 (16 B). Writer lane l covers k0 = l*4.
__global__ __launch_bounds__(256) void normalize_k(
    const float* __restrict__ ex, const float* __restrict__ ey,
    _Float16* __restrict__ xn, _Float16* __restrict__ yn) {
  const int lane = threadIdx.x & 63;
  const int row = blockIdx.x * 4 + (threadIdx.x >> 6);
  const float* src;
  _Float16* dst;
  int r;
  if (row < NROWS) {
    src = ex + (size_t)row * KDIM;
    dst = xn;
    r = row;
  } else {
    src = ey + (size_t)(row - NROWS) * KDIM;
    dst = yn;
    r = row - NROWS;
  }
  float4 v = *reinterpret_cast<const float4*>(src + lane * 4);
  float ss = v.x * v.x + v.y * v.y + v.z * v.z + v.w * v.w;
#pragma unroll
  for (int m = 1; m <= 32; m <<= 1) ss += __shfl_xor(ss, m, 64);
  float inv = 1.0f / fmaxf(sqrtf(ss), 1e-8f);
  f16x4 o;
  o[0] = (_Float16)(v.x * inv);
  o[1] = (_Float16)(v.y * inv);
  o[2] = (_Float16)(v.z * inv);
  o[3] = (_Float16)(v.w * inv);
  const int kb = lane >> 2, h = (lane >> 1) & 1, sub = lane & 1;
  const size_t chunk = (size_t)(r >> 5) * 16 + kb;   // *1024 B = *512 halves
  const size_t off = chunk * 512 + (h * 32 + (r & 31)) * 8 + sub * 4;
  *reinterpret_cast<f16x4*>(dst + off) = o;
}

// ------------------------------ GEMM + max ---------------------------------
// 256x256 tile, 8 waves (2x4), wave-tile 128x64, mfma_f32_32x32x16_f16.
// LDS ring: 3 x [A 8KB | B 8KB] = 48 KB, + 2 KB reduce = 50 KB.
__global__ __launch_bounds__(512, 2) void gemm_max_k(
    const _Float16* __restrict__ Xf, const _Float16* __restrict__ Yf,
    unsigned* __restrict__ rmax, unsigned* __restrict__ cmax) {
  __shared__ __align__(16) char smem[51200];

  const int tid = threadIdx.x;
  const int lane = tid & 63;
  const int wid = tid >> 6;  // 0..7
  const int wr = wid >> 2;   // 0..1 : rows wr*128..+127
  const int wc = wid & 3;    // 0..3 : cols wc*64..+63

  // XCD-square traversal: XCD x owns tm in [x*8,x*8+8) x all tn; traversed
  // in 8x8 squares (2 MB working set, L2-resident; A band persists).
  const int bid = blockIdx.x;
  const int x = bid & 7;
  const int lid = bid >> 3;       // 0..511, sequential per XCD
  const int sq = lid >> 6;        // 0..7   (which 8-wide tn square)
  const int r8 = lid & 63;
  const int tm = x * 8 + (r8 >> 3);
  const int tn = sq * 8 + (r8 & 7);

  // staging source pointers (halves): wave w owns chunk w of A and of B.
  // chunk(rb, kb) at halves offset rb*8192 + kb*512; per-lane +lane*8.
  const _Float16* xa = Xf + (size_t)(tm * 8 + wid) * 8192 + lane * 8;
  const _Float16* ya = Yf + (size_t)(tn * 8 + wid) * 8192 + lane * 8;

  unsigned* red = (unsigned*)(smem + 49152);  // [256] rows | [256] cols
  red[tid] = 0;
  __syncthreads();

  // ---- stage step u into ring buffer u%3 (2 gl_lds per wave) ----
  auto stage = [&](int u) {
    const int bo = (u % 3) * 16384;
    gl_lds16(xa + u * 512, smem + bo + wid * 1024 + lane * 16);
    gl_lds16(ya + u * 512, smem + bo + 8192 + wid * 1024 + lane * 16);
  };

  // fragment LDS byte offsets within a ring buffer
  int aoff[4], boff[2];
#pragma unroll
  for (int m = 0; m < 4; ++m) aoff[m] = (wr * 4 + m) * 1024 + lane * 16;
#pragma unroll
  for (int n = 0; n < 2; ++n) boff[n] = 8192 + (wc * 2 + n) * 1024 + lane * 16;

  f32x16 acc[4][2] = {};

  stage(0);
  stage(1);

#pragma unroll
  for (int kt = 0; kt < 16; ++kt) {
    // my stage(kt) must be retired; stage(kt+1)'s 2 loads stay in flight.
    if (kt < 15)
      asm volatile("s_waitcnt vmcnt(2)" ::: "memory");
    else
      asm volatile("s_waitcnt vmcnt(0)" ::: "memory");
    __builtin_amdgcn_sched_barrier(0);
    __builtin_amdgcn_s_barrier();  // all waves' slice-kt chunks landed
    __builtin_amdgcn_sched_barrier(0);
    if (kt + 2 < 16) stage(kt + 2);  // after barrier: buf (kt+2)%3 is free
    const int bo = (kt % 3) * 16384;
    f16x8 a0 = *(const f16x8*)(smem + bo + aoff[0]);
    f16x8 a1 = *(const f16x8*)(smem + bo + aoff[1]);
    f16x8 a2 = *(const f16x8*)(smem + bo + aoff[2]);
    f16x8 a3 = *(const f16x8*)(smem + bo + aoff[3]);
    f16x8 b0 = *(const f16x8*)(smem + bo + boff[0]);
    f16x8 b1 = *(const f16x8*)(smem + bo + boff[1]);
    __builtin_amdgcn_s_setprio(1);
    acc[0][0] = __builtin_amdgcn_mfma_f32_32x32x16_f16(a0, b0, acc[0][0], 0, 0, 0);
    acc[0][1] = __builtin_amdgcn_mfma_f32_32x32x16_f16(a0, b1, acc[0][1], 0, 0, 0);
    acc[1][0] = __builtin_amdgcn_mfma_f32_32x32x16_f16(a1, b0, acc[1][0], 0, 0, 0);
    acc[1][1] = __builtin_amdgcn_mfma_f32_32x32x16_f16(a1, b1, acc[1][1], 0, 0, 0);
    acc[2][0] = __builtin_amdgcn_mfma_f32_32x32x16_f16(a2, b0, acc[2][0], 0, 0, 0);
    acc[2][1] = __builtin_amdgcn_mfma_f32_32x32x16_f16(a2, b1, acc[2][1], 0, 0, 0);
    acc[3][0] = __builtin_amdgcn_mfma_f32_32x32x16_f16(a3, b0, acc[3][0], 0, 0, 0);
    acc[3][1] = __builtin_amdgcn_mfma_f32_32x32x16_f16(a3, b1, acc[3][1], 0, 0, 0);
    __builtin_amdgcn_s_setprio(0);
  }

  // ---- epilogue ----
  // C/D 32x32 layout: col = lane&31, row = (r&3) + 8*(r>>2) + 4*(lane>>5)
#pragma unroll
  for (int m = 0; m < 4; ++m) {
#pragma unroll
    for (int r = 0; r < 16; ++r) {
      float v = fmaxf(acc[m][0][r], acc[m][1][r]);
      v = dppmax<0x128>(v);  // row_ror:8
      v = dppmax<0x124>(v);  // row_ror:4
      v = dppmax<0x122>(v);  // row_ror:2
      v = dppmax<0x121>(v);  // row_ror:1
      v = fmaxf(v, __shfl_xor(v, 16, 64));
      if ((lane & 31) == 0)
        atomicMax(&red[wr * 128 + m * 32 + (r & 3) + 8 * (r >> 2) +
                       4 * (lane >> 5)],
                  f2mono(v));
    }
  }
#pragma unroll
  for (int n = 0; n < 2; ++n) {
    float v = acc[0][n][0];
#pragma unroll
    for (int m = 0; m < 4; ++m)
#pragma unroll
      for (int r = 0; r < 16; ++r) v = fmaxf(v, acc[m][n][r]);
    v = fmaxf(v, __shfl_xor(v, 32, 64));
    if (lane < 32) atomicMax(&red[256 + wc * 64 + n * 32 + lane], f2mono(v));
  }
  __syncthreads();

  if (tid < 256)
    atomicMax(&rmax[tm * 256 + tid], red[tid]);
  else
    atomicMax(&cmax[tn * 256 + (tid - 256)], red[tid]);
}

// ------------------------------ finalize -----------------------------------
__global__ __launch_bounds__(256) void finalize_k(
    const unsigned* __restrict__ rmax, const unsigned* __restrict__ cmax,
    float* __restrict__ out) {
  const unsigned* src = (blockIdx.x == 0) ? rmax : cmax;
  float sum = 0.0f;
  for (int i = threadIdx.x; i < NROWS; i += 256) {
    float v = mono2f(src[i]);
    float d = v - 1.0f;
    // lp = -d^2/(2*0.3^2) - (log(0.3)+0.5*log(2pi))
    float lp = fmaf(-d * d, 5.5555555556f, 0.2850342717f);
    sum += expf(lp) * lp;
  }
#pragma unroll
  for (int m = 1; m <= 32; m <<= 1) sum += __shfl_xor(sum, m, 64);
  __shared__ float partial[4];
  if ((threadIdx.x & 63) == 0) partial[threadIdx.x >> 6] = sum;
  __syncthreads();
  if (threadIdx.x == 0)
    out[blockIdx.x] = -(partial[0] + partial[1] + partial[2] + partial[3]);
}

// ---------------------------------------------------------------------------
extern "C" void kernel_launch(void* const* d_in, const int* in_sizes, int n_in,
                              void* d_out, int out_size, void* d_ws, size_t ws_size,
                              hipStream_t stream) {
  const float* ex = (const float*)d_in[0];
  const float* ey = (const float*)d_in[1];
  char* wsb = (char*)d_ws;
  // ws layout: xn f16 8MB (tiled) | yn f16 8MB (tiled) | rmax 64KB | cmax 64KB
  _Float16* xn = (_Float16*)wsb;
  _Float16* yn = (_Float16*)(wsb + 8388608);
  unsigned* rmax = (unsigned*)(wsb + 16777216);
  unsigned* cmax = (unsigned*)(wsb + 16777216 + 65536);

  (void)hipMemsetAsync(wsb + 16777216, 0, 131072, stream);  // mono-floor = 0
  normalize_k<<<8192, 256, 0, stream>>>(ex, ey, xn, yn);
  gemm_max_k<<<4096, 512, 0, stream>>>(xn, yn, rmax, cmax);
  finalize_k<<<2, 256, 0, stream>>>(rmax, cmax, (float*)d_out);
}